// Round 1
// baseline (460.660 us; speedup 1.0000x reference)
//
#include <hip/hip_runtime.h>
#include <hip/hip_bf16.h>

typedef __bf16 bf16;
typedef __bf16 bf16x8 __attribute__((ext_vector_type(8)));
typedef float f32x4 __attribute__((ext_vector_type(4)));

// workspace layout (bytes)
#define WS_INV 262144           // 512 f32
#define WS_ADD 264192           // 512 f32
#define WS_BIAS 266240          // 16*64*64 f32 = 256KB

#define XS_STRIDE 264           // bf16 elems per xs row (528B, 16B aligned)
#define QK_STRIDE 520           // bf16 elems per qk row (1040B, 16B aligned)
#define LDS_AVG_OFF 66560       // 64*1040
#define LDS_BYTES (66560 + 2048)

// ---------------- prep: w->bf16, BN fold, bias table ----------------
__global__ void prep_kernel(const float* __restrict__ w_qk,
                            const float* __restrict__ gamma,
                            const float* __restrict__ beta,
                            const float* __restrict__ rmean,
                            const float* __restrict__ rvar,
                            const float* __restrict__ rel_table,
                            char* __restrict__ ws) {
  bf16* wbf = (bf16*)ws;
  float* invb = (float*)(ws + WS_INV);
  float* addb = (float*)(ws + WS_ADD);
  float* biasb = (float*)(ws + WS_BIAS);
  int bid = blockIdx.x, t = threadIdx.x;
  if (bid < 512) {
    int o = bid;
    wbf[o * 256 + t] = (bf16)w_qk[o * 256 + t];
    if (t == 0) {
      float iv = gamma[o] * rsqrtf(rvar[o] + 1e-5f);
      invb[o] = iv;
      addb[o] = beta[o] - rmean[o] * iv;
    }
  } else {
    int base = (bid - 512) * 1024 + t * 4;
#pragma unroll
    for (int i = 0; i < 4; ++i) {
      int flat = base + i;
      int h = flat >> 12, n = (flat >> 6) & 63, m = flat & 63;
      int idx = ((n >> 3) - (m >> 3) + 7) * 15 + ((n & 7) - (m & 7) + 7);
      biasb[flat] = rel_table[idx * 16 + h];
    }
  }
}

// ---------------- fused: conv1x1+BN+ReLU -> QK^T+bias -> softmax+avg ----------------
__global__ __launch_bounds__(512)
void fused_kernel(const float* __restrict__ x, const char* __restrict__ ws,
                  float* __restrict__ out_attn, float* __restrict__ out_avg) {
  const bf16* __restrict__ wbf = (const bf16*)ws;
  const float* __restrict__ invb = (const float*)(ws + WS_INV);
  const float* __restrict__ addb = (const float*)(ws + WS_ADD);
  const float* __restrict__ biasb = (const float*)(ws + WS_BIAS);

  __shared__ __attribute__((aligned(16))) char smem[LDS_BYTES];
  bf16* xs = (bf16*)smem;                       // [64 px][264] (phase 1-2)
  bf16* qk = (bf16*)smem;                       // [64 px][520] (phase 2-3, overlapped)
  float* avgp = (float*)(smem + LDS_AVG_OFF);   // [8][64]

  const int bid = blockIdx.x;
  const int win = (bid & 7) * 144 + (bid >> 3);   // XCD-bijective swizzle (1152 = 8*144)
  const int b = win / 576;
  const int rem = win - b * 576;
  const int wy = rem / 24, wx = rem - (rem / 24) * 24;

  const int tid = threadIdx.x;
  const int w = tid >> 6;     // wave 0..7
  const int l = tid & 63;
  const int lg = l >> 4;      // 4-lane-group id 0..3
  const int ll = l & 15;

  // ---- phase 1: stage x window -> xs[px][c] bf16 (transposed, padded) ----
  {
    const float* xb = x + (size_t)b * 256 * 36864 + (size_t)(wy * 8) * 192 + wx * 8;
    const int c = tid & 255;
    const int half = tid >> 8;   // 0..1
#pragma unroll
    for (int p = 0; p < 4; ++p) {
      int ws1 = p * 2 + half;
      const float* src = xb + (size_t)c * 36864 + ws1 * 192;
      float4 v0 = *(const float4*)src;
      float4 v1 = *(const float4*)(src + 4);
      bf16* dst = xs + (ws1 * 8) * XS_STRIDE + c;
      dst[0 * XS_STRIDE] = (bf16)v0.x;
      dst[1 * XS_STRIDE] = (bf16)v0.y;
      dst[2 * XS_STRIDE] = (bf16)v0.z;
      dst[3 * XS_STRIDE] = (bf16)v0.w;
      dst[4 * XS_STRIDE] = (bf16)v1.x;
      dst[5 * XS_STRIDE] = (bf16)v1.y;
      dst[6 * XS_STRIDE] = (bf16)v1.z;
      dst[7 * XS_STRIDE] = (bf16)v1.w;
    }
  }
  __syncthreads();

  // ---- phase 2: GEMM1.  wave w owns out-channels [w*64, w*64+64) x all 64 px ----
  f32x4 acc[4][4];
#pragma unroll
  for (int mt = 0; mt < 4; ++mt)
#pragma unroll
    for (int nt = 0; nt < 4; ++nt)
      acc[mt][nt] = (f32x4){0.f, 0.f, 0.f, 0.f};

  const int obase = w * 64;
  for (int kk = 0; kk < 8; ++kk) {
    bf16x8 a[4], bb[4];
#pragma unroll
    for (int mt = 0; mt < 4; ++mt)   // A[o][c] direct from L2-resident bf16 w
      a[mt] = *(const bf16x8*)(wbf + (size_t)(obase + mt * 16 + ll) * 256 + kk * 32 + lg * 8);
#pragma unroll
    for (int nt = 0; nt < 4; ++nt)   // B[c][px] from xs (row-major [px][c])
      bb[nt] = *(const bf16x8*)(xs + (nt * 16 + ll) * XS_STRIDE + kk * 32 + lg * 8);
#pragma unroll
    for (int mt = 0; mt < 4; ++mt)
#pragma unroll
      for (int nt = 0; nt < 4; ++nt)
        acc[mt][nt] = __builtin_amdgcn_mfma_f32_16x16x32_bf16(a[mt], bb[nt], acc[mt][nt], 0, 0, 0);
  }
  __syncthreads();   // all waves done reading xs; qk overlaps it

  // epilogue: BN + ReLU -> qk[px][o] bf16
#pragma unroll
  for (int mt = 0; mt < 4; ++mt) {
#pragma unroll
    for (int j = 0; j < 4; ++j) {
      int o = obase + mt * 16 + lg * 4 + j;     // D row
      float iv = invb[o], ad = addb[o];
#pragma unroll
      for (int nt = 0; nt < 4; ++nt) {
        int px = nt * 16 + ll;                  // D col
        float v = fmaxf(acc[mt][nt][j] * iv + ad, 0.f);
        qk[px * QK_STRIDE + o] = (bf16)v;
      }
    }
  }
  __syncthreads();

  // ---- phase 3: per wave, 2 heads: dots (MFMA, K padded 16->32), softmax, avg ----
  bf16x8 zfrag;
#pragma unroll
  for (int i = 0; i < 8; ++i) zfrag[i] = (bf16)0.f;

  float psum[4] = {0.f, 0.f, 0.f, 0.f};

  for (int hh = 0; hh < 2; ++hh) {
    const int h = w * 2 + hh;
    bf16x8 qa[4];
#pragma unroll
    for (int nt = 0; nt < 4; ++nt) {   // A[n][dk] = q^T ; lanes>=32 are the K-pad -> zero
      bf16x8 v = *(const bf16x8*)(qk + (nt * 16 + ll) * QK_STRIDE + h * 16 + (lg & 1) * 8);
      qa[nt] = (l < 32) ? v : zfrag;
    }
    f32x4 s[4][4];
#pragma unroll
    for (int mt = 0; mt < 4; ++mt) {
      bf16x8 kb = *(const bf16x8*)(qk + (mt * 16 + ll) * QK_STRIDE + 256 + h * 16 + (lg & 1) * 8);
      kb = (l < 32) ? kb : zfrag;
#pragma unroll
      for (int nt = 0; nt < 4; ++nt) {
        f32x4 z = {0.f, 0.f, 0.f, 0.f};
        s[nt][mt] = __builtin_amdgcn_mfma_f32_16x16x32_bf16(qa[nt], kb, z, 0, 0, 0);
      }
    }
    // scale + bias, accumulate avg partial
    const float* bh = biasb + h * 4096;
#pragma unroll
    for (int nt = 0; nt < 4; ++nt) {
#pragma unroll
      for (int j = 0; j < 4; ++j) {
        int n = nt * 16 + lg * 4 + j;
#pragma unroll
        for (int mt = 0; mt < 4; ++mt) {
          float v = s[nt][mt][j] * 0.25f + bh[n * 64 + mt * 16 + ll];
          s[nt][mt][j] = v;
          psum[mt] += v;
        }
      }
    }
    // wave-parallel softmax over rows (16 lanes hold a row's 64 cols as 4 regs)
#pragma unroll
    for (int nt = 0; nt < 4; ++nt) {
#pragma unroll
      for (int j = 0; j < 4; ++j) {
        float mx = fmaxf(fmaxf(s[nt][0][j], s[nt][1][j]), fmaxf(s[nt][2][j], s[nt][3][j]));
        mx = fmaxf(mx, __shfl_xor(mx, 1));
        mx = fmaxf(mx, __shfl_xor(mx, 2));
        mx = fmaxf(mx, __shfl_xor(mx, 4));
        mx = fmaxf(mx, __shfl_xor(mx, 8));
        float sum = 0.f;
#pragma unroll
        for (int mt = 0; mt < 4; ++mt) {
          float e = __expf(s[nt][mt][j] - mx);
          s[nt][mt][j] = e;
          sum += e;
        }
        sum += __shfl_xor(sum, 1);
        sum += __shfl_xor(sum, 2);
        sum += __shfl_xor(sum, 4);
        sum += __shfl_xor(sum, 8);
        float rinv = __builtin_amdgcn_rcpf(sum);
        int n = nt * 16 + lg * 4 + j;
        float* orow = out_attn + ((size_t)(win * 16 + h) * 64 + n) * 64 + ll;
#pragma unroll
        for (int mt = 0; mt < 4; ++mt)
          orow[mt * 16] = s[nt][mt][j] * rinv;
      }
    }
  }

  // ---- avg reduction: psum holds sum over (this wave's 2 heads, own rows) for col m ----
#pragma unroll
  for (int mt = 0; mt < 4; ++mt) {
    psum[mt] += __shfl_xor(psum[mt], 16);
    psum[mt] += __shfl_xor(psum[mt], 32);
  }
  if (l < 16) {
#pragma unroll
    for (int mt = 0; mt < 4; ++mt)
      avgp[w * 64 + mt * 16 + l] = psum[mt];
  }
  __syncthreads();
  if (tid < 64) {
    float t = 0.f;
#pragma unroll
    for (int w2 = 0; w2 < 8; ++w2) t += avgp[w2 * 64 + tid];
    out_avg[win * 64 + tid] = t * (1.f / 1024.f);
  }
}

extern "C" void kernel_launch(void* const* d_in, const int* in_sizes, int n_in,
                              void* d_out, int out_size, void* d_ws, size_t ws_size,
                              hipStream_t stream) {
  const float* x     = (const float*)d_in[0];
  const float* w_qk  = (const float*)d_in[1];
  const float* gamma = (const float*)d_in[2];
  const float* beta  = (const float*)d_in[3];
  const float* rmean = (const float*)d_in[4];
  const float* rvar  = (const float*)d_in[5];
  const float* rel   = (const float*)d_in[6];
  float* out = (float*)d_out;
  char* ws = (char*)d_ws;

  prep_kernel<<<576, 256, 0, stream>>>(w_qk, gamma, beta, rmean, rvar, rel, ws);
  fused_kernel<<<1152, 512, 0, stream>>>(x, ws, out, out + (size_t)75497472);
}

// Round 2
// 451.659 us; speedup vs baseline: 1.0199x; 1.0199x over previous
//
#include <hip/hip_runtime.h>
#include <hip/hip_bf16.h>

typedef __bf16 bf16;
typedef __bf16 bf16x4 __attribute__((ext_vector_type(4)));
typedef __bf16 bf16x8 __attribute__((ext_vector_type(8)));
typedef float f32x4 __attribute__((ext_vector_type(4)));

// workspace layout (bytes)
#define WS_INV 262144           // 512 f32
#define WS_ADD 264192           // 512 f32
#define WS_BIAS 266240          // 16*64*64 f32 = 256KB

#define XS_STRIDE 264           // bf16 elems per xs row (528B, 16B aligned)
#define QK_STRIDE 520           // bf16 elems per qk row (1040B, 16B aligned)
#define LDS_AVG_OFF 66560       // 64*1040
#define LDS_STG_OFF 68608       // avg + 2KB
#define STG_STRIDE 68           // f32 per staged row (4 rows per wave, 272 dw/wave)
#define LDS_BYTES (68608 + 8704)

// ---------------- prep: w->bf16, BN fold, bias table ----------------
__global__ void prep_kernel(const float* __restrict__ w_qk,
                            const float* __restrict__ gamma,
                            const float* __restrict__ beta,
                            const float* __restrict__ rmean,
                            const float* __restrict__ rvar,
                            const float* __restrict__ rel_table,
                            char* __restrict__ ws) {
  bf16* wbf = (bf16*)ws;
  float* invb = (float*)(ws + WS_INV);
  float* addb = (float*)(ws + WS_ADD);
  float* biasb = (float*)(ws + WS_BIAS);
  int bid = blockIdx.x, t = threadIdx.x;
  if (bid < 512) {
    int o = bid;
    wbf[o * 256 + t] = (bf16)w_qk[o * 256 + t];
    if (t == 0) {
      float iv = gamma[o] * rsqrtf(rvar[o] + 1e-5f);
      invb[o] = iv;
      addb[o] = beta[o] - rmean[o] * iv;
    }
  } else {
    int base = (bid - 512) * 1024 + t * 4;
#pragma unroll
    for (int i = 0; i < 4; ++i) {
      int flat = base + i;
      int h = flat >> 12, n = (flat >> 6) & 63, m = flat & 63;
      int idx = ((n >> 3) - (m >> 3) + 7) * 15 + ((n & 7) - (m & 7) + 7);
      biasb[flat] = rel_table[idx * 16 + h];
    }
  }
}

// ---------------- fused: conv1x1+BN+ReLU -> QK^T+bias -> softmax+avg ----------------
__global__ __launch_bounds__(512)
void fused_kernel(const float* __restrict__ x, const char* __restrict__ ws,
                  float* __restrict__ out_attn, float* __restrict__ out_avg) {
  const bf16* __restrict__ wbf = (const bf16*)ws;
  const float* __restrict__ invb = (const float*)(ws + WS_INV);
  const float* __restrict__ addb = (const float*)(ws + WS_ADD);
  const float* __restrict__ biasb = (const float*)(ws + WS_BIAS);

  __shared__ __attribute__((aligned(16))) char smem[LDS_BYTES];
  bf16* xs = (bf16*)smem;                       // [64 px][264] (phase 1-2)
  bf16* qk = (bf16*)smem;                       // [64 px][520] (phase 2-3, overlapped)
  float* avgp = (float*)(smem + LDS_AVG_OFF);   // [8][64]

  const int bid = blockIdx.x;
  const int win = (bid & 7) * 144 + (bid >> 3);   // XCD-bijective swizzle (1152 = 8*144)
  const int b = win / 576;
  const int rem = win - b * 576;
  const int wy = rem / 24, wx = rem - (rem / 24) * 24;

  const int tid = threadIdx.x;
  const int w = tid >> 6;     // wave 0..7
  const int l = tid & 63;
  const int lg = l >> 4;      // 4-lane-group id 0..3
  const int ll = l & 15;

  float* stgw = (float*)(smem + LDS_STG_OFF) + w * (4 * STG_STRIDE);  // per-wave [4][68] f32

  // ---- phase 1: stage x window -> xs[px][c] bf16 (transposed, padded) ----
  {
    const float* xb = x + (size_t)b * 256 * 36864 + (size_t)(wy * 8) * 192 + wx * 8;
    const int c = tid & 255;
    const int half = tid >> 8;   // 0..1
#pragma unroll
    for (int p = 0; p < 4; ++p) {
      int ws1 = p * 2 + half;
      const float* src = xb + (size_t)c * 36864 + ws1 * 192;
      float4 v0 = *(const float4*)src;
      float4 v1 = *(const float4*)(src + 4);
      bf16* dst = xs + (ws1 * 8) * XS_STRIDE + c;
      dst[0 * XS_STRIDE] = (bf16)v0.x;
      dst[1 * XS_STRIDE] = (bf16)v0.y;
      dst[2 * XS_STRIDE] = (bf16)v0.z;
      dst[3 * XS_STRIDE] = (bf16)v0.w;
      dst[4 * XS_STRIDE] = (bf16)v1.x;
      dst[5 * XS_STRIDE] = (bf16)v1.y;
      dst[6 * XS_STRIDE] = (bf16)v1.z;
      dst[7 * XS_STRIDE] = (bf16)v1.w;
    }
  }
  __syncthreads();

  // ---- phase 2: GEMM1.  wave w owns out-channels [w*64, w*64+64) x all 64 px ----
  f32x4 acc[4][4];
#pragma unroll
  for (int mt = 0; mt < 4; ++mt)
#pragma unroll
    for (int nt = 0; nt < 4; ++nt)
      acc[mt][nt] = (f32x4){0.f, 0.f, 0.f, 0.f};

  const int obase = w * 64;
  for (int kk = 0; kk < 8; ++kk) {
    bf16x8 a[4], bb[4];
#pragma unroll
    for (int mt = 0; mt < 4; ++mt)   // A[o][c] direct from L2-resident bf16 w
      a[mt] = *(const bf16x8*)(wbf + (size_t)(obase + mt * 16 + ll) * 256 + kk * 32 + lg * 8);
#pragma unroll
    for (int nt = 0; nt < 4; ++nt)   // B[c][px] from xs (row-major [px][c])
      bb[nt] = *(const bf16x8*)(xs + (nt * 16 + ll) * XS_STRIDE + kk * 32 + lg * 8);
#pragma unroll
    for (int mt = 0; mt < 4; ++mt)
#pragma unroll
      for (int nt = 0; nt < 4; ++nt)
        acc[mt][nt] = __builtin_amdgcn_mfma_f32_16x16x32_bf16(a[mt], bb[nt], acc[mt][nt], 0, 0, 0);
  }
  __syncthreads();   // all waves done reading xs; qk overlaps it

  // epilogue: BN + ReLU -> qk[px][o] bf16  (vector ds_write_b64, 2-way banks = free)
#pragma unroll
  for (int mt = 0; mt < 4; ++mt) {
    const int ob = obase + mt * 16 + lg * 4;
    float iv0 = invb[ob + 0], iv1 = invb[ob + 1], iv2 = invb[ob + 2], iv3 = invb[ob + 3];
    float ad0 = addb[ob + 0], ad1 = addb[ob + 1], ad2 = addb[ob + 2], ad3 = addb[ob + 3];
#pragma unroll
    for (int nt = 0; nt < 4; ++nt) {
      int px = nt * 16 + ll;
      bf16x4 pack;
      pack[0] = (bf16)fmaxf(acc[mt][nt][0] * iv0 + ad0, 0.f);
      pack[1] = (bf16)fmaxf(acc[mt][nt][1] * iv1 + ad1, 0.f);
      pack[2] = (bf16)fmaxf(acc[mt][nt][2] * iv2 + ad2, 0.f);
      pack[3] = (bf16)fmaxf(acc[mt][nt][3] * iv3 + ad3, 0.f);
      *(bf16x4*)(qk + px * QK_STRIDE + ob) = pack;
    }
  }
  __syncthreads();

  // ---- phase 3: per wave, 2 heads: dots (MFMA, K padded 16->32), softmax, avg ----
  bf16x8 zfrag;
#pragma unroll
  for (int i = 0; i < 8; ++i) zfrag[i] = (bf16)0.f;

  float psum[4] = {0.f, 0.f, 0.f, 0.f};

  for (int hh = 0; hh < 2; ++hh) {
    const int h = w * 2 + hh;
    bf16x8 qa[4];
#pragma unroll
    for (int nt = 0; nt < 4; ++nt) {   // A[n][dk] = q^T ; lanes>=32 are the K-pad -> zero
      bf16x8 v = *(const bf16x8*)(qk + (nt * 16 + ll) * QK_STRIDE + h * 16 + (lg & 1) * 8);
      qa[nt] = (l < 32) ? v : zfrag;
    }
    f32x4 s[4][4];
#pragma unroll
    for (int mt = 0; mt < 4; ++mt) {
      bf16x8 kb = *(const bf16x8*)(qk + (mt * 16 + ll) * QK_STRIDE + 256 + h * 16 + (lg & 1) * 8);
      kb = (l < 32) ? kb : zfrag;
#pragma unroll
      for (int nt = 0; nt < 4; ++nt) {
        f32x4 z = {0.f, 0.f, 0.f, 0.f};
        s[nt][mt] = __builtin_amdgcn_mfma_f32_16x16x32_bf16(qa[nt], kb, z, 0, 0, 0);
      }
    }
    // scale + bias, accumulate avg partial
    const float* bh = biasb + h * 4096;
#pragma unroll
    for (int nt = 0; nt < 4; ++nt) {
#pragma unroll
      for (int j = 0; j < 4; ++j) {
        int n = nt * 16 + lg * 4 + j;
#pragma unroll
        for (int mt = 0; mt < 4; ++mt) {
          float v = s[nt][mt][j] * 0.25f + bh[n * 64 + mt * 16 + ll];
          s[nt][mt][j] = v;
          psum[mt] += v;
        }
      }
    }
    // wave-parallel softmax over rows (16 lanes hold a row's 64 cols as 4 regs),
    // then stage the normalized row through LDS so global stores are 256B-contiguous/row
#pragma unroll
    for (int nt = 0; nt < 4; ++nt) {
#pragma unroll
      for (int j = 0; j < 4; ++j) {
        float mx = fmaxf(fmaxf(s[nt][0][j], s[nt][1][j]), fmaxf(s[nt][2][j], s[nt][3][j]));
        mx = fmaxf(mx, __shfl_xor(mx, 1));
        mx = fmaxf(mx, __shfl_xor(mx, 2));
        mx = fmaxf(mx, __shfl_xor(mx, 4));
        mx = fmaxf(mx, __shfl_xor(mx, 8));
        float sum = 0.f;
#pragma unroll
        for (int mt = 0; mt < 4; ++mt) {
          float e = __expf(s[nt][mt][j] - mx);
          s[nt][mt][j] = e;
          sum += e;
        }
        sum += __shfl_xor(sum, 1);
        sum += __shfl_xor(sum, 2);
        sum += __shfl_xor(sum, 4);
        sum += __shfl_xor(sum, 8);
        float rinv = __builtin_amdgcn_rcpf(sum);
        // stage row (lg owns row n = nt*16+lg*4+j) into [4][68] f32, 2-way banks on write
#pragma unroll
        for (int mt = 0; mt < 4; ++mt)
          stgw[lg * STG_STRIDE + mt * 16 + ll] = s[nt][mt][j] * rinv;
        // same-wave lockstep: compiler inserts lgkmcnt wait before aliasing read
        f32x4 v = *(const f32x4*)(stgw + lg * STG_STRIDE + 4 * ll);
        int n = nt * 16 + lg * 4 + j;
        *(f32x4*)(out_attn + ((size_t)(win * 16 + h) * 64 + n) * 64 + 4 * ll) = v;
      }
    }
  }

  // ---- avg reduction: psum holds sum over (this wave's 2 heads, own rows) for col m ----
#pragma unroll
  for (int mt = 0; mt < 4; ++mt) {
    psum[mt] += __shfl_xor(psum[mt], 16);
    psum[mt] += __shfl_xor(psum[mt], 32);
  }
  if (l < 16) {
#pragma unroll
    for (int mt = 0; mt < 4; ++mt)
      avgp[w * 64 + mt * 16 + l] = psum[mt];
  }
  __syncthreads();
  if (tid < 64) {
    float t = 0.f;
#pragma unroll
    for (int w2 = 0; w2 < 8; ++w2) t += avgp[w2 * 64 + tid];
    out_avg[win * 64 + tid] = t * (1.f / 1024.f);
  }
}

extern "C" void kernel_launch(void* const* d_in, const int* in_sizes, int n_in,
                              void* d_out, int out_size, void* d_ws, size_t ws_size,
                              hipStream_t stream) {
  const float* x     = (const float*)d_in[0];
  const float* w_qk  = (const float*)d_in[1];
  const float* gamma = (const float*)d_in[2];
  const float* beta  = (const float*)d_in[3];
  const float* rmean = (const float*)d_in[4];
  const float* rvar  = (const float*)d_in[5];
  const float* rel   = (const float*)d_in[6];
  float* out = (float*)d_out;
  char* ws = (char*)d_ws;

  prep_kernel<<<576, 256, 0, stream>>>(w_qk, gamma, beta, rmean, rvar, rel, ws);
  fused_kernel<<<1152, 512, 0, stream>>>(x, ws, out, out + (size_t)75497472);
}